// Round 5
// baseline (442.171 us; speedup 1.0000x reference)
//
#include <hip/hip_runtime.h>
#include <hip/hip_bf16.h>
#include <math.h>

#define N_NODES 50000
#define N_EDGES 800000
#define NH 4
#define ND 64
#define NF 256   // NH*ND = feature width everywhere (IN=256 too)
#define NC 16
#define NEG_SLOPE 0.2f

typedef __attribute__((ext_vector_type(8))) short bf16x8;
typedef __attribute__((ext_vector_type(4))) float f32x4;

__device__ __forceinline__ float elu_f(float x) {
    return x > 0.f ? x : (__expf(x) - 1.f);
}

__device__ __forceinline__ ushort bf16_rne(float f) {
    union { float f; unsigned u; } v; v.f = f;
    unsigned u = v.u;
    u += 0x7fffu + ((u >> 16) & 1u);   // round-to-nearest-even
    return (ushort)(u >> 16);
}

__device__ __forceinline__ float bf2f(ushort u) {
    return __uint_as_float(((unsigned)u) << 16);
}

// ---------------- cast x (f32) -> bf16 ----------------
__global__ __launch_bounds__(256) void cast_bf16_kernel(const float* __restrict__ in,
                                                        ushort* __restrict__ out, int n8) {
    int i = blockIdx.x * 256 + threadIdx.x;
    if (i >= n8) return;
    float4 a = *(const float4*)(in + i * 8);
    float4 b = *(const float4*)(in + i * 8 + 4);
    ushort o[8] = {bf16_rne(a.x), bf16_rne(a.y), bf16_rne(a.z), bf16_rne(a.w),
                   bf16_rne(b.x), bf16_rne(b.y), bf16_rne(b.z), bf16_rne(b.w)};
    *(bf16x8*)(out + i * 8) = *(bf16x8*)o;
}

// ---- transpose+cast W[k][n] f32 -> Wt[n][k] bf16, two weights in one launch ----
__global__ __launch_bounds__(256) void castWt_kernel(const float* __restrict__ W0,
                                                     const float* __restrict__ W1,
                                                     ushort* __restrict__ Wt0,
                                                     ushort* __restrict__ Wt1) {
    const float* W = (blockIdx.x < 256) ? W0 : W1;
    ushort* Wt = (blockIdx.x < 256) ? Wt0 : Wt1;
    int n = blockIdx.x & 255;
    int k = threadIdx.x;
    Wt[n * 256 + k] = bf16_rne(W[k * 256 + n]);
}

// ---------------- GEMM: Cbf[M,256]bf16 = A[M,256]bf16 @ Bt[n][k]bf16 ----------------
// 128x128 tile, BK=64, 256 threads (4 waves 2x2), 16x16x32 MFMA, XOR-swizzled LDS.
// Fused epilogue: el/er = dot(feat_row, al/ar) per head (16-lane shfl reduce).
__global__ __launch_bounds__(256) void gemm_bf16(const ushort* __restrict__ A,
                                                 const ushort* __restrict__ Bt,
                                                 ushort* __restrict__ Cbf,
                                                 const float* __restrict__ al,
                                                 const float* __restrict__ ar,
                                                 float* __restrict__ el,
                                                 float* __restrict__ er, int M) {
    __shared__ __align__(16) ushort As[128 * 64];   // [row][k], 16B blocks XOR-swizzled
    __shared__ __align__(16) ushort Bs[128 * 64];   // [col][k], same
    const int t = threadIdx.x;
    const int l = t & 63;
    const int w = t >> 6;
    const int wm = (w >> 1) * 64, wn = (w & 1) * 64;
    const int m0 = blockIdx.x * 128, n0 = blockIdx.y * 128;
    const int lr = l & 15, lk = l >> 4;

    f32x4 acc[4][4] = {};
    const int sr = t >> 3;            // staging row-in-issue 0..31
    const int sc = t & 7;             // global 16B-block col
    const int scw = sc ^ (sr & 7);    // swizzled LDS block

    for (int k0 = 0; k0 < 256; k0 += 64) {
        #pragma unroll
        for (int q = 0; q < 4; ++q) {
            int row = q * 32 + sr;
            int ga = min(m0 + row, M - 1);
            bf16x8 va = *(const bf16x8*)(A + (size_t)ga * 256 + k0 + sc * 8);
            *(bf16x8*)(&As[row * 64 + scw * 8]) = va;
            bf16x8 vb = *(const bf16x8*)(Bt + (size_t)(n0 + row) * 256 + k0 + sc * 8);
            *(bf16x8*)(&Bs[row * 64 + scw * 8]) = vb;
        }
        __syncthreads();
        #pragma unroll
        for (int kk = 0; kk < 2; ++kk) {
            bf16x8 af[4], bfr[4];
            #pragma unroll
            for (int mi = 0; mi < 4; ++mi) {
                int row = wm + mi * 16 + lr;
                int kb = kk * 4 + lk;
                af[mi] = *(const bf16x8*)(&As[row * 64 + (kb ^ (row & 7)) * 8]);
            }
            #pragma unroll
            for (int ni = 0; ni < 4; ++ni) {
                int col = wn + ni * 16 + lr;
                int kb = kk * 4 + lk;
                bfr[ni] = *(const bf16x8*)(&Bs[col * 64 + (kb ^ (col & 7)) * 8]);
            }
            #pragma unroll
            for (int mi = 0; mi < 4; ++mi)
                #pragma unroll
                for (int ni = 0; ni < 4; ++ni)
                    acc[mi][ni] = __builtin_amdgcn_mfma_f32_16x16x32_bf16(af[mi], bfr[ni], acc[mi][ni], 0, 0, 0);
        }
        __syncthreads();
    }
    // this wave's head and its al/ar slice (d = ni*16 + lr)
    const int h = (n0 + wn) >> 6;
    float alv[4], arv[4];
    #pragma unroll
    for (int ni = 0; ni < 4; ++ni) {
        alv[ni] = al[h * ND + ni * 16 + lr];
        arv[ni] = ar[h * ND + ni * 16 + lr];
    }
    // C/D layout: col = lane&15, row = (lane>>4)*4 + reg  [m89-verified]
    #pragma unroll
    for (int mi = 0; mi < 4; ++mi) {
        #pragma unroll
        for (int j = 0; j < 4; ++j) {
            int row = m0 + wm + mi * 16 + lk * 4 + j;
            float pe = 0.f, pr = 0.f;
            #pragma unroll
            for (int ni = 0; ni < 4; ++ni) {
                float v = acc[mi][ni][j];
                pe += v * alv[ni];
                pr += v * arv[ni];
                if (row < M)
                    Cbf[(size_t)row * 256 + n0 + wn + ni * 16 + lr] = bf16_rne(v);
            }
            #pragma unroll
            for (int m = 1; m <= 8; m <<= 1) {
                pe += __shfl_xor(pe, m, 64);
                pr += __shfl_xor(pr, m, 64);
            }
            if (lr == 0 && row < M) {
                el[row * 4 + h] = pe;
                er[row * 4 + h] = pr;
            }
        }
    }
}

// -------- CSR build --------
__global__ __launch_bounds__(256) void hist_kernel(const int* __restrict__ dst, int* __restrict__ count) {
    int e = blockIdx.x * 256 + threadIdx.x;
    if (e < N_EDGES) atomicAdd(&count[dst[e]], 1);
}

__global__ __launch_bounds__(256) void scan1_kernel(const int* __restrict__ counts,
                                                    int* __restrict__ offs,
                                                    int* __restrict__ bsums) {
    __shared__ int sh[256];
    int tid = threadIdx.x;
    int i = blockIdx.x * 256 + tid;
    int v = (i < N_NODES) ? counts[i] : 0;
    sh[tid] = v;
    __syncthreads();
    #pragma unroll
    for (int ofs = 1; ofs < 256; ofs <<= 1) {
        int t = (tid >= ofs) ? sh[tid - ofs] : 0;
        __syncthreads();
        sh[tid] += t;
        __syncthreads();
    }
    if (i < N_NODES) offs[i] = sh[tid] - v;
    if (tid == 255) bsums[blockIdx.x] = sh[255];
}

__global__ __launch_bounds__(256) void scan2_kernel(const int* __restrict__ bsums,
                                                    int* __restrict__ boffs, int nb) {
    __shared__ int sh[256];
    int tid = threadIdx.x;
    int v = (tid < nb) ? bsums[tid] : 0;
    sh[tid] = v;
    __syncthreads();
    #pragma unroll
    for (int ofs = 1; ofs < 256; ofs <<= 1) {
        int t = (tid >= ofs) ? sh[tid - ofs] : 0;
        __syncthreads();
        sh[tid] += t;
        __syncthreads();
    }
    if (tid < nb) boffs[tid] = sh[tid] - v;
}

// scan3: finalize offs AND init cursor (absolute write positions)
__global__ __launch_bounds__(256) void scan3_kernel(int* __restrict__ offs,
                                                    const int* __restrict__ boffs,
                                                    int* __restrict__ cursor) {
    int i = blockIdx.x * 256 + threadIdx.x;
    if (i < N_NODES) {
        int v = offs[i] + boffs[i >> 8];
        offs[i] = v;
        cursor[i] = v;
    }
    if (i == 0) offs[N_NODES] = N_EDGES;
}

// scatter: store src AND dst node ids per slot
__global__ __launch_bounds__(256) void scatter_kernel(const int* __restrict__ src,
                                                      const int* __restrict__ dst,
                                                      int* __restrict__ cursor,
                                                      int* __restrict__ csrc,
                                                      int* __restrict__ cdst) {
    int e = blockIdx.x * 256 + threadIdx.x;
    if (e >= N_EDGES) return;
    int d = dst[e];
    int p = atomicAdd(&cursor[d], 1);
    csrc[p] = src[e];
    cdst[p] = d;
}

// -------- per-slot attention weights: w[i][h] = exp(leaky(el[src]+er[dst])) --------
__global__ __launch_bounds__(256) void edge_w_kernel(const int* __restrict__ csrc,
                                                     const int* __restrict__ cdst,
                                                     const float* __restrict__ el,
                                                     const float* __restrict__ er,
                                                     float* __restrict__ w) {
    int i = blockIdx.x * 256 + threadIdx.x;
    if (i >= N_EDGES) return;
    int s = csrc[i], d = cdst[i];
    float4 lv = *(const float4*)(el + s * 4);
    float4 rv = *(const float4*)(er + d * 4);
    float lvv[4] = {lv.x, lv.y, lv.z, lv.w};
    float rvv[4] = {rv.x, rv.y, rv.z, rv.w};
    float o[4];
    #pragma unroll
    for (int hh = 0; hh < 4; ++hh) {
        float v = lvv[hh] + rvv[hh];
        v = v > 0.f ? v : NEG_SLOPE * v;
        o[hh] = __expf(v);
    }
    *(float4*)(w + (size_t)i * 4) = make_float4(o[0], o[1], o[2], o[3]);
}

// -------- aggregation: lane = 8-feature chunk (16B loads), 2 edges per load instr --------
// wave per node; half = lane>>5 takes even/odd slots; 16-edge chunks = 8 in-flight 16B loads.
// AGG_LOOP leaves: acc[8] (per-lane partial), dsum (per-lane partial), combined across halves.
#define AGG_LOOP()                                                              \
    for (int i = s0; i < s1; i += 16) {                                         \
        float wv[8]; int sidv[8];                                               \
        _Pragma("unroll")                                                       \
        for (int u = 0; u < 8; ++u) {                                           \
            int sl = i + 2 * u + half;                                          \
            int idx = sl < s1 ? sl : s1 - 1;                                    \
            sidv[u] = csrc[idx];                                                \
            wv[u] = sl < s1 ? w[(size_t)idx * 4 + h] : 0.f;                     \
        }                                                                       \
        bf16x8 fv[8];                                                           \
        _Pragma("unroll")                                                       \
        for (int u = 0; u < 8; ++u)                                             \
            fv[u] = *(const bf16x8*)(featbf + (size_t)sidv[u] * NF + sub * 8);  \
        _Pragma("unroll")                                                       \
        for (int u = 0; u < 8; ++u) {                                           \
            dsum += wv[u];                                                      \
            _Pragma("unroll")                                                   \
            for (int j = 0; j < 8; ++j)                                         \
                acc[j] += wv[u] * bf2f((ushort)fv[u][j]);                       \
        }                                                                       \
    }                                                                           \
    _Pragma("unroll")                                                           \
    for (int j = 0; j < 8; ++j) acc[j] += __shfl_xor(acc[j], 32, 64);           \
    dsum += __shfl_xor(dsum, 32, 64);

__global__ __launch_bounds__(256, 4) void agg_l0_kernel(const ushort* __restrict__ featbf,
                                                        const int* __restrict__ csrc,
                                                        const int* __restrict__ offs,
                                                        const float* __restrict__ w,
                                                        ushort* __restrict__ out_bf) {
    int n = blockIdx.x * 4 + (threadIdx.x >> 6);
    int lane = threadIdx.x & 63;
    int half = lane >> 5;
    int sub = lane & 31;      // feature chunk: feats [sub*8, sub*8+8)
    int h = sub >> 3;         // head owning this chunk
    int s0 = offs[n], s1 = offs[n + 1];
    float acc[8] = {};
    float dsum = 0.f;
    AGG_LOOP()
    float inv = 1.f / fmaxf(dsum, 1e-9f);
    if (half == 0) {
        ushort o[8];
        #pragma unroll
        for (int j = 0; j < 8; ++j) o[j] = bf16_rne(elu_f(acc[j] * inv));
        *(bf16x8*)(out_bf + (size_t)n * NF + sub * 8) = *(bf16x8*)o;
    }
}

// -------- final: aggregation + elu + heads write + cluster softmax --------
__global__ __launch_bounds__(256, 4) void agg_final_kernel(const ushort* __restrict__ featbf,
                                                           const int* __restrict__ csrc,
                                                           const int* __restrict__ offs,
                                                           const float* __restrict__ w,
                                                           const float* __restrict__ Wc,
                                                           const float* __restrict__ bc,
                                                           float* __restrict__ out) {
    int n = blockIdx.x * 4 + (threadIdx.x >> 6);
    int lane = threadIdx.x & 63;
    int half = lane >> 5;
    int sub = lane & 31;
    int h = sub >> 3;
    int d0 = (sub & 7) * 8;   // within-head feature offset
    int s0 = offs[n], s1 = offs[n + 1];
    float acc[8] = {};
    float dsum = 0.f;
    AGG_LOOP()
    float inv = 1.f / fmaxf(dsum, 1e-9f);
    float v[8];
    #pragma unroll
    for (int j = 0; j < 8; ++j) v[j] = elu_f(acc[j] * inv);
    size_t base = (size_t)h * N_NODES * (ND + NC) + (size_t)n * (ND + NC);
    if (half == 0) {
        *(float4*)(out + base + d0)     = make_float4(v[0], v[1], v[2], v[3]);
        *(float4*)(out + base + d0 + 4) = make_float4(v[4], v[5], v[6], v[7]);
    }
    // cluster logits: partial over this lane's 8 feats, butterfly over the head's 8 lanes
    float logit[NC];
    #pragma unroll
    for (int c = 0; c < NC; ++c) {
        float p = 0.f;
        #pragma unroll
        for (int j = 0; j < 8; ++j)
            p += v[j] * Wc[(d0 + j) * NC + c];
        p += __shfl_xor(p, 1, 64);
        p += __shfl_xor(p, 2, 64);
        p += __shfl_xor(p, 4, 64);
        logit[c] = p + bc[c];
    }
    float m = logit[0];
    #pragma unroll
    for (int c = 1; c < NC; ++c) m = fmaxf(m, logit[c]);
    float ssum = 0.f;
    #pragma unroll
    for (int c = 0; c < NC; ++c) ssum += __expf(logit[c] - m);
    if (half == 0) {
        int g0 = (sub & 7) * 2;
        float2 pr = make_float2(__expf(logit[g0] - m) / ssum,
                                __expf(logit[g0 + 1] - m) / ssum);
        *(float2*)(out + base + ND + g0) = pr;
    }
}

extern "C" void kernel_launch(void* const* d_in, const int* in_sizes, int n_in,
                              void* d_out, int out_size, void* d_ws, size_t ws_size,
                              hipStream_t stream) {
    const float* x   = (const float*)d_in[0];
    const int* src   = (const int*)d_in[1];
    const int* dst   = (const int*)d_in[2];
    const float* W0  = (const float*)d_in[3];
    const float* al0 = (const float*)d_in[4];
    const float* ar0 = (const float*)d_in[5];
    const float* W1  = (const float*)d_in[6];
    const float* al1 = (const float*)d_in[7];
    const float* ar1 = (const float*)d_in[8];
    const float* Wc  = (const float*)d_in[9];
    const float* bc  = (const float*)d_in[10];
    float* out = (float*)d_out;

    char* ws = (char*)d_ws;
    size_t off = 0;
    auto alloc = [&](size_t bytes) { void* p = ws + off; off = (off + bytes + 255) & ~(size_t)255; return p; };
    ushort* featbf = (ushort*)alloc((size_t)N_NODES * NF * 2);   // 25.6 MB (GEMM out, bf16)
    ushort* xbf    = (ushort*)alloc((size_t)N_NODES * NF * 2);   // 25.6 MB
    ushort* hbuf   = (ushort*)alloc((size_t)N_NODES * NF * 2);   // 25.6 MB (layer0 out, bf16)
    ushort* Wt0    = (ushort*)alloc((size_t)256 * 256 * 2);
    ushort* Wt1    = (ushort*)alloc((size_t)256 * 256 * 2);
    float*  el     = (float*)alloc((size_t)N_NODES * NH * 4);
    float*  er     = (float*)alloc((size_t)N_NODES * NH * 4);
    float*  wbuf   = (float*)alloc((size_t)N_EDGES * NH * 4);    // 12.8 MB per-slot weights
    int* counts    = (int*)alloc((size_t)N_NODES * 4);
    int* offs      = (int*)alloc((size_t)(N_NODES + 1) * 4);
    int* cursor    = (int*)alloc((size_t)N_NODES * 4);
    int* csrc      = (int*)alloc((size_t)N_EDGES * 4);
    int* cdst      = (int*)alloc((size_t)N_EDGES * 4);
    int* bsums     = (int*)alloc(256 * 4);
    int* boffs     = (int*)alloc(256 * 4);

    const int EB = (N_EDGES + 255) / 256;          // 3125
    const int NB = (N_NODES + 255) / 256;          // 196
    const int GEMM_MB = (N_NODES + 127) / 128;     // 391
    const int C8 = (N_NODES * NF / 8 + 255) / 256;

    // ---- CSR build (stores src+dst ids per slot) ----
    hipMemsetAsync(counts, 0, (size_t)N_NODES * 4, stream);
    hist_kernel<<<EB, 256, 0, stream>>>(dst, counts);
    scan1_kernel<<<NB, 256, 0, stream>>>(counts, offs, bsums);
    scan2_kernel<<<1, 256, 0, stream>>>(bsums, boffs, NB);
    scan3_kernel<<<NB, 256, 0, stream>>>(offs, boffs, cursor);
    scatter_kernel<<<EB, 256, 0, stream>>>(src, dst, cursor, csrc, cdst);

    // ---- weight + input casts ----
    castWt_kernel<<<512, 256, 0, stream>>>(W0, W1, Wt0, Wt1);
    cast_bf16_kernel<<<C8, 256, 0, stream>>>(x, xbf, N_NODES * NF / 8);

    // ---- Layer 0 ----
    gemm_bf16<<<dim3(GEMM_MB, 2), 256, 0, stream>>>(xbf, Wt0, featbf, al0, ar0, el, er, N_NODES);
    edge_w_kernel<<<EB, 256, 0, stream>>>(csrc, cdst, el, er, wbuf);
    agg_l0_kernel<<<N_NODES / 4, 256, 0, stream>>>(featbf, csrc, offs, wbuf, hbuf);

    // ---- Layer 1 ----
    gemm_bf16<<<dim3(GEMM_MB, 2), 256, 0, stream>>>(hbuf, Wt1, featbf, al1, ar1, el, er, N_NODES);
    edge_w_kernel<<<EB, 256, 0, stream>>>(csrc, cdst, el, er, wbuf);
    agg_final_kernel<<<N_NODES / 4, 256, 0, stream>>>(featbf, csrc, offs, wbuf, Wc, bc, out);
}

// Round 6
// 440.116 us; speedup vs baseline: 1.0047x; 1.0047x over previous
//
#include <hip/hip_runtime.h>
#include <hip/hip_bf16.h>
#include <math.h>

#define N_NODES 50000
#define N_EDGES 800000
#define NH 4
#define ND 64
#define NF 256   // NH*ND = feature width everywhere (IN=256 too)
#define NC 16
#define NEG_SLOPE 0.2f
#define AGG_CHUNK 16   // edges staged per chunk (8 dual-row global_load_lds)

typedef __attribute__((ext_vector_type(8))) short bf16x8;
typedef __attribute__((ext_vector_type(4))) float f32x4;

__device__ __forceinline__ float elu_f(float x) {
    return x > 0.f ? x : (__expf(x) - 1.f);
}

__device__ __forceinline__ ushort bf16_rne(float f) {
    union { float f; unsigned u; } v; v.f = f;
    unsigned u = v.u;
    u += 0x7fffu + ((u >> 16) & 1u);   // round-to-nearest-even
    return (ushort)(u >> 16);
}

__device__ __forceinline__ float bf2f(ushort u) {
    return __uint_as_float(((unsigned)u) << 16);
}

// async global->LDS: each lane writes 16B at ldsbase + lane*16 [m97/m104 semantics]
__device__ __forceinline__ void row_pair_to_lds(const ushort* gp, char* lp) {
    __builtin_amdgcn_global_load_lds(
        (const __attribute__((address_space(1))) unsigned int*)gp,
        (__attribute__((address_space(3))) unsigned int*)lp,
        16, 0, 0);
}

// ---------------- cast x (f32) -> bf16 ----------------
__global__ __launch_bounds__(256) void cast_bf16_kernel(const float* __restrict__ in,
                                                        ushort* __restrict__ out, int n8) {
    int i = blockIdx.x * 256 + threadIdx.x;
    if (i >= n8) return;
    float4 a = *(const float4*)(in + i * 8);
    float4 b = *(const float4*)(in + i * 8 + 4);
    ushort o[8] = {bf16_rne(a.x), bf16_rne(a.y), bf16_rne(a.z), bf16_rne(a.w),
                   bf16_rne(b.x), bf16_rne(b.y), bf16_rne(b.z), bf16_rne(b.w)};
    *(bf16x8*)(out + i * 8) = *(bf16x8*)o;
}

// ---- transpose+cast W[k][n] f32 -> Wt[n][k] bf16, two weights in one launch ----
__global__ __launch_bounds__(256) void castWt_kernel(const float* __restrict__ W0,
                                                     const float* __restrict__ W1,
                                                     ushort* __restrict__ Wt0,
                                                     ushort* __restrict__ Wt1) {
    const float* W = (blockIdx.x < 256) ? W0 : W1;
    ushort* Wt = (blockIdx.x < 256) ? Wt0 : Wt1;
    int n = blockIdx.x & 255;
    int k = threadIdx.x;
    Wt[n * 256 + k] = bf16_rne(W[k * 256 + n]);
}

// ---------------- GEMM: Cbf[M,256]bf16 = A[M,256]bf16 @ Bt[n][k]bf16 ----------------
// 128x128 tile, BK=64, 256 threads (4 waves 2x2), 16x16x32 MFMA, XOR-swizzled LDS.
// Fused epilogue: el/er = dot(feat_row, al/ar) per head (16-lane shfl reduce).
__global__ __launch_bounds__(256) void gemm_bf16(const ushort* __restrict__ A,
                                                 const ushort* __restrict__ Bt,
                                                 ushort* __restrict__ Cbf,
                                                 const float* __restrict__ al,
                                                 const float* __restrict__ ar,
                                                 float* __restrict__ el,
                                                 float* __restrict__ er, int M) {
    __shared__ __align__(16) ushort As[128 * 64];   // [row][k], 16B blocks XOR-swizzled
    __shared__ __align__(16) ushort Bs[128 * 64];   // [col][k], same
    const int t = threadIdx.x;
    const int l = t & 63;
    const int w = t >> 6;
    const int wm = (w >> 1) * 64, wn = (w & 1) * 64;
    const int m0 = blockIdx.x * 128, n0 = blockIdx.y * 128;
    const int lr = l & 15, lk = l >> 4;

    f32x4 acc[4][4] = {};
    const int sr = t >> 3;            // staging row-in-issue 0..31
    const int sc = t & 7;             // global 16B-block col
    const int scw = sc ^ (sr & 7);    // swizzled LDS block

    for (int k0 = 0; k0 < 256; k0 += 64) {
        #pragma unroll
        for (int q = 0; q < 4; ++q) {
            int row = q * 32 + sr;
            int ga = min(m0 + row, M - 1);
            bf16x8 va = *(const bf16x8*)(A + (size_t)ga * 256 + k0 + sc * 8);
            *(bf16x8*)(&As[row * 64 + scw * 8]) = va;
            bf16x8 vb = *(const bf16x8*)(Bt + (size_t)(n0 + row) * 256 + k0 + sc * 8);
            *(bf16x8*)(&Bs[row * 64 + scw * 8]) = vb;
        }
        __syncthreads();
        #pragma unroll
        for (int kk = 0; kk < 2; ++kk) {
            bf16x8 af[4], bfr[4];
            #pragma unroll
            for (int mi = 0; mi < 4; ++mi) {
                int row = wm + mi * 16 + lr;
                int kb = kk * 4 + lk;
                af[mi] = *(const bf16x8*)(&As[row * 64 + (kb ^ (row & 7)) * 8]);
            }
            #pragma unroll
            for (int ni = 0; ni < 4; ++ni) {
                int col = wn + ni * 16 + lr;
                int kb = kk * 4 + lk;
                bfr[ni] = *(const bf16x8*)(&Bs[col * 64 + (kb ^ (col & 7)) * 8]);
            }
            #pragma unroll
            for (int mi = 0; mi < 4; ++mi)
                #pragma unroll
                for (int ni = 0; ni < 4; ++ni)
                    acc[mi][ni] = __builtin_amdgcn_mfma_f32_16x16x32_bf16(af[mi], bfr[ni], acc[mi][ni], 0, 0, 0);
        }
        __syncthreads();
    }
    // this wave's head and its al/ar slice (d = ni*16 + lr)
    const int h = (n0 + wn) >> 6;
    float alv[4], arv[4];
    #pragma unroll
    for (int ni = 0; ni < 4; ++ni) {
        alv[ni] = al[h * ND + ni * 16 + lr];
        arv[ni] = ar[h * ND + ni * 16 + lr];
    }
    // C/D layout: col = lane&15, row = (lane>>4)*4 + reg  [m89-verified]
    #pragma unroll
    for (int mi = 0; mi < 4; ++mi) {
        #pragma unroll
        for (int j = 0; j < 4; ++j) {
            int row = m0 + wm + mi * 16 + lk * 4 + j;
            float pe = 0.f, pr = 0.f;
            #pragma unroll
            for (int ni = 0; ni < 4; ++ni) {
                float v = acc[mi][ni][j];
                pe += v * alv[ni];
                pr += v * arv[ni];
                if (row < M)
                    Cbf[(size_t)row * 256 + n0 + wn + ni * 16 + lr] = bf16_rne(v);
            }
            #pragma unroll
            for (int m = 1; m <= 8; m <<= 1) {
                pe += __shfl_xor(pe, m, 64);
                pr += __shfl_xor(pr, m, 64);
            }
            if (lr == 0 && row < M) {
                el[row * 4 + h] = pe;
                er[row * 4 + h] = pr;
            }
        }
    }
}

// -------- CSR build --------
__global__ __launch_bounds__(256) void hist_kernel(const int* __restrict__ dst, int* __restrict__ count) {
    int e = blockIdx.x * 256 + threadIdx.x;
    if (e < N_EDGES) atomicAdd(&count[dst[e]], 1);
}

__global__ __launch_bounds__(256) void scan1_kernel(const int* __restrict__ counts,
                                                    int* __restrict__ offs,
                                                    int* __restrict__ bsums) {
    __shared__ int sh[256];
    int tid = threadIdx.x;
    int i = blockIdx.x * 256 + tid;
    int v = (i < N_NODES) ? counts[i] : 0;
    sh[tid] = v;
    __syncthreads();
    #pragma unroll
    for (int ofs = 1; ofs < 256; ofs <<= 1) {
        int t = (tid >= ofs) ? sh[tid - ofs] : 0;
        __syncthreads();
        sh[tid] += t;
        __syncthreads();
    }
    if (i < N_NODES) offs[i] = sh[tid] - v;
    if (tid == 255) bsums[blockIdx.x] = sh[255];
}

__global__ __launch_bounds__(256) void scan2_kernel(const int* __restrict__ bsums,
                                                    int* __restrict__ boffs, int nb) {
    __shared__ int sh[256];
    int tid = threadIdx.x;
    int v = (tid < nb) ? bsums[tid] : 0;
    sh[tid] = v;
    __syncthreads();
    #pragma unroll
    for (int ofs = 1; ofs < 256; ofs <<= 1) {
        int t = (tid >= ofs) ? sh[tid - ofs] : 0;
        __syncthreads();
        sh[tid] += t;
        __syncthreads();
    }
    if (tid < nb) boffs[tid] = sh[tid] - v;
}

// scan3: finalize offs AND init cursor (absolute write positions)
__global__ __launch_bounds__(256) void scan3_kernel(int* __restrict__ offs,
                                                    const int* __restrict__ boffs,
                                                    int* __restrict__ cursor) {
    int i = blockIdx.x * 256 + threadIdx.x;
    if (i < N_NODES) {
        int v = offs[i] + boffs[i >> 8];
        offs[i] = v;
        cursor[i] = v;
    }
    if (i == 0) offs[N_NODES] = N_EDGES;
}

// scatter: store src AND dst node ids per slot
__global__ __launch_bounds__(256) void scatter_kernel(const int* __restrict__ src,
                                                      const int* __restrict__ dst,
                                                      int* __restrict__ cursor,
                                                      int* __restrict__ csrc,
                                                      int* __restrict__ cdst) {
    int e = blockIdx.x * 256 + threadIdx.x;
    if (e >= N_EDGES) return;
    int d = dst[e];
    int p = atomicAdd(&cursor[d], 1);
    csrc[p] = src[e];
    cdst[p] = d;
}

// -------- per-slot attention weights: w[i][h] = exp(leaky(el[src]+er[dst])) --------
__global__ __launch_bounds__(256) void edge_w_kernel(const int* __restrict__ csrc,
                                                     const int* __restrict__ cdst,
                                                     const float* __restrict__ el,
                                                     const float* __restrict__ er,
                                                     float* __restrict__ w) {
    int i = blockIdx.x * 256 + threadIdx.x;
    if (i >= N_EDGES) return;
    int s = csrc[i], d = cdst[i];
    float4 lv = *(const float4*)(el + s * 4);
    float4 rv = *(const float4*)(er + d * 4);
    float lvv[4] = {lv.x, lv.y, lv.z, lv.w};
    float rvv[4] = {rv.x, rv.y, rv.z, rv.w};
    float o[4];
    #pragma unroll
    for (int hh = 0; hh < 4; ++hh) {
        float v = lvv[hh] + rvv[hh];
        v = v > 0.f ? v : NEG_SLOPE * v;
        o[hh] = __expf(v);
    }
    *(float4*)(w + (size_t)i * 4) = make_float4(o[0], o[1], o[2], o[3]);
}

// -------- aggregation via async LDS staging --------
// one wave per node; per 16-edge chunk: 8 dual-row global_load_lds (no data VGPRs,
// 16 rows outstanding), explicit vmcnt(0), then FMA from LDS. Scalarized loop bounds.
// AGG_STAGE_LOOP leaves acc (float4, feats [lane*4, lane*4+4)) and dsum.
#define AGG_STAGE_LOOP()                                                          \
    for (int i = s0; i < s1; i += AGG_CHUNK) {                                    \
        int sid[AGG_CHUNK]; float wv[AGG_CHUNK];                                  \
        _Pragma("unroll")                                                         \
        for (int u = 0; u < AGG_CHUNK; ++u) {                                     \
            int sl = i + u;                                                       \
            int idx = sl < s1 ? sl : s1 - 1;                                      \
            sid[u] = csrc[idx];                                                   \
            wv[u] = sl < s1 ? w[(size_t)idx * 4 + h] : 0.f;                       \
        }                                                                         \
        _Pragma("unroll")                                                         \
        for (int u = 0; u < AGG_CHUNK / 2; ++u) {                                 \
            int s2 = rowsel ? sid[2 * u + 1] : sid[2 * u];                        \
            const ushort* gp = featbf + (size_t)s2 * NF + bsub * 8;               \
            row_pair_to_lds(gp, myl + u * 1024);                                  \
        }                                                                         \
        asm volatile("s_waitcnt vmcnt(0)" ::: "memory");                          \
        __builtin_amdgcn_sched_barrier(0);                                        \
        _Pragma("unroll")                                                         \
        for (int u = 0; u < AGG_CHUNK; ++u) {                                     \
            ushort4 fr = *(const ushort4*)(myl + u * 512 + lane * 8);             \
            dsum += wv[u];                                                        \
            acc.x += wv[u] * bf2f(fr.x);                                          \
            acc.y += wv[u] * bf2f(fr.y);                                          \
            acc.z += wv[u] * bf2f(fr.z);                                          \
            acc.w += wv[u] * bf2f(fr.w);                                          \
        }                                                                         \
    }

__global__ __launch_bounds__(256) void agg_l0_kernel(const ushort* __restrict__ featbf,
                                                     const int* __restrict__ csrc,
                                                     const int* __restrict__ offs,
                                                     const float* __restrict__ w,
                                                     ushort* __restrict__ out_bf) {
    __shared__ __align__(16) char ldsbuf[4][AGG_CHUNK * 512];   // 32 KB: 8KB per wave
    int wid = threadIdx.x >> 6;
    char* myl = &ldsbuf[wid][0];
    int n = __builtin_amdgcn_readfirstlane(blockIdx.x * 4 + wid);
    int lane = threadIdx.x & 63;
    int h = lane >> 4;
    int rowsel = lane >> 5;
    int bsub = lane & 31;
    int s0 = __builtin_amdgcn_readfirstlane(offs[n]);
    int s1 = __builtin_amdgcn_readfirstlane(offs[n + 1]);
    float4 acc = make_float4(0.f, 0.f, 0.f, 0.f);
    float dsum = 0.f;
    AGG_STAGE_LOOP()
    float inv = 1.f / fmaxf(dsum, 1e-9f);
    ushort o[4] = {bf16_rne(elu_f(acc.x * inv)), bf16_rne(elu_f(acc.y * inv)),
                   bf16_rne(elu_f(acc.z * inv)), bf16_rne(elu_f(acc.w * inv))};
    *(ushort4*)(out_bf + (size_t)n * NF + lane * 4) = *(ushort4*)o;
}

// -------- final: aggregation + elu + heads write + cluster softmax --------
__global__ __launch_bounds__(256) void agg_final_kernel(const ushort* __restrict__ featbf,
                                                        const int* __restrict__ csrc,
                                                        const int* __restrict__ offs,
                                                        const float* __restrict__ w,
                                                        const float* __restrict__ Wc,
                                                        const float* __restrict__ bc,
                                                        float* __restrict__ out) {
    __shared__ __align__(16) char ldsbuf[4][AGG_CHUNK * 512];   // 32 KB: 8KB per wave
    int wid = threadIdx.x >> 6;
    char* myl = &ldsbuf[wid][0];
    int n = __builtin_amdgcn_readfirstlane(blockIdx.x * 4 + wid);
    int lane = threadIdx.x & 63;
    int h = lane >> 4;
    int g = lane & 15;
    int rowsel = lane >> 5;
    int bsub = lane & 31;
    int s0 = __builtin_amdgcn_readfirstlane(offs[n]);
    int s1 = __builtin_amdgcn_readfirstlane(offs[n + 1]);
    float4 acc = make_float4(0.f, 0.f, 0.f, 0.f);
    float dsum = 0.f;
    AGG_STAGE_LOOP()
    float inv = 1.f / fmaxf(dsum, 1e-9f);
    float v0 = elu_f(acc.x * inv), v1 = elu_f(acc.y * inv);
    float v2 = elu_f(acc.z * inv), v3 = elu_f(acc.w * inv);
    size_t base = (size_t)h * N_NODES * (ND + NC) + (size_t)n * (ND + NC);
    *(float4*)(out + base + g * 4) = make_float4(v0, v1, v2, v3);
    float logit[NC];
    #pragma unroll
    for (int c = 0; c < NC; ++c) {
        int d0 = g * 4;
        float p = v0 * Wc[(d0 + 0) * NC + c] + v1 * Wc[(d0 + 1) * NC + c] +
                  v2 * Wc[(d0 + 2) * NC + c] + v3 * Wc[(d0 + 3) * NC + c];
        p += __shfl_xor(p, 1, 64);
        p += __shfl_xor(p, 2, 64);
        p += __shfl_xor(p, 4, 64);
        p += __shfl_xor(p, 8, 64);
        logit[c] = p + bc[c];
    }
    float m = logit[0];
    #pragma unroll
    for (int c = 1; c < NC; ++c) m = fmaxf(m, logit[c]);
    float ssum = 0.f;
    #pragma unroll
    for (int c = 0; c < NC; ++c) ssum += __expf(logit[c] - m);
    out[base + ND + g] = __expf(logit[g] - m) / ssum;
}

extern "C" void kernel_launch(void* const* d_in, const int* in_sizes, int n_in,
                              void* d_out, int out_size, void* d_ws, size_t ws_size,
                              hipStream_t stream) {
    const float* x   = (const float*)d_in[0];
    const int* src   = (const int*)d_in[1];
    const int* dst   = (const int*)d_in[2];
    const float* W0  = (const float*)d_in[3];
    const float* al0 = (const float*)d_in[4];
    const float* ar0 = (const float*)d_in[5];
    const float* W1  = (const float*)d_in[6];
    const float* al1 = (const float*)d_in[7];
    const float* ar1 = (const float*)d_in[8];
    const float* Wc  = (const float*)d_in[9];
    const float* bc  = (const float*)d_in[10];
    float* out = (float*)d_out;

    char* ws = (char*)d_ws;
    size_t off = 0;
    auto alloc = [&](size_t bytes) { void* p = ws + off; off = (off + bytes + 255) & ~(size_t)255; return p; };
    ushort* featbf = (ushort*)alloc((size_t)N_NODES * NF * 2);   // 25.6 MB (GEMM out, bf16)
    ushort* xbf    = (ushort*)alloc((size_t)N_NODES * NF * 2);   // 25.6 MB
    ushort* hbuf   = (ushort*)alloc((size_t)N_NODES * NF * 2);   // 25.6 MB (layer0 out, bf16)
    ushort* Wt0    = (ushort*)alloc((size_t)256 * 256 * 2);
    ushort* Wt1    = (ushort*)alloc((size_t)256 * 256 * 2);
    float*  el     = (float*)alloc((size_t)N_NODES * NH * 4);
    float*  er     = (float*)alloc((size_t)N_NODES * NH * 4);
    float*  wbuf   = (float*)alloc((size_t)N_EDGES * NH * 4);    // 12.8 MB per-slot weights
    int* counts    = (int*)alloc((size_t)N_NODES * 4);
    int* offs      = (int*)alloc((size_t)(N_NODES + 1) * 4);
    int* cursor    = (int*)alloc((size_t)N_NODES * 4);
    int* csrc      = (int*)alloc((size_t)N_EDGES * 4);
    int* cdst      = (int*)alloc((size_t)N_EDGES * 4);
    int* bsums     = (int*)alloc(256 * 4);
    int* boffs     = (int*)alloc(256 * 4);

    const int EB = (N_EDGES + 255) / 256;          // 3125
    const int NB = (N_NODES + 255) / 256;          // 196
    const int GEMM_MB = (N_NODES + 127) / 128;     // 391
    const int C8 = (N_NODES * NF / 8 + 255) / 256;

    // ---- CSR build (stores src+dst ids per slot) ----
    hipMemsetAsync(counts, 0, (size_t)N_NODES * 4, stream);
    hist_kernel<<<EB, 256, 0, stream>>>(dst, counts);
    scan1_kernel<<<NB, 256, 0, stream>>>(counts, offs, bsums);
    scan2_kernel<<<1, 256, 0, stream>>>(bsums, boffs, NB);
    scan3_kernel<<<NB, 256, 0, stream>>>(offs, boffs, cursor);
    scatter_kernel<<<EB, 256, 0, stream>>>(src, dst, cursor, csrc, cdst);

    // ---- weight + input casts ----
    castWt_kernel<<<512, 256, 0, stream>>>(W0, W1, Wt0, Wt1);
    cast_bf16_kernel<<<C8, 256, 0, stream>>>(x, xbf, N_NODES * NF / 8);

    // ---- Layer 0 ----
    gemm_bf16<<<dim3(GEMM_MB, 2), 256, 0, stream>>>(xbf, Wt0, featbf, al0, ar0, el, er, N_NODES);
    edge_w_kernel<<<EB, 256, 0, stream>>>(csrc, cdst, el, er, wbuf);
    agg_l0_kernel<<<N_NODES / 4, 256, 0, stream>>>(featbf, csrc, offs, wbuf, hbuf);

    // ---- Layer 1 ----
    gemm_bf16<<<dim3(GEMM_MB, 2), 256, 0, stream>>>(hbuf, Wt1, featbf, al1, ar1, el, er, N_NODES);
    edge_w_kernel<<<EB, 256, 0, stream>>>(csrc, cdst, el, er, wbuf);
    agg_final_kernel<<<N_NODES / 4, 256, 0, stream>>>(featbf, csrc, offs, wbuf, Wc, bc, out);
}

// Round 7
// 364.698 us; speedup vs baseline: 1.2124x; 1.2068x over previous
//
#include <hip/hip_runtime.h>
#include <hip/hip_bf16.h>
#include <math.h>

#define N_NODES 50000
#define N_EDGES 800000
#define NH 4
#define ND 64
#define NF 256   // NH*ND = feature width everywhere (IN=256 too)
#define NC 16
#define NEG_SLOPE 0.2f
#define AGG_CHUNK 16   // edges staged per chunk (8 dual-row global_load_lds)

typedef __attribute__((ext_vector_type(8))) short bf16x8;
typedef __attribute__((ext_vector_type(4))) float f32x4;

__device__ __forceinline__ float elu_f(float x) {
    return x > 0.f ? x : (__expf(x) - 1.f);
}

__device__ __forceinline__ ushort bf16_rne(float f) {
    union { float f; unsigned u; } v; v.f = f;
    unsigned u = v.u;
    u += 0x7fffu + ((u >> 16) & 1u);   // round-to-nearest-even
    return (ushort)(u >> 16);
}

__device__ __forceinline__ float bf2f(ushort u) {
    return __uint_as_float(((unsigned)u) << 16);
}

// async global->LDS: each active lane writes 16B at ldsbase + lane*16 [m97/m104 semantics]
__device__ __forceinline__ void row_pair_to_lds(const ushort* gp, char* lp) {
    __builtin_amdgcn_global_load_lds(
        (const __attribute__((address_space(1))) unsigned int*)gp,
        (__attribute__((address_space(3))) unsigned int*)lp,
        16, 0, 0);
}

// ---------------- cast x (f32) -> bf16 ----------------
__global__ __launch_bounds__(256) void cast_bf16_kernel(const float* __restrict__ in,
                                                        ushort* __restrict__ out, int n8) {
    int i = blockIdx.x * 256 + threadIdx.x;
    if (i >= n8) return;
    float4 a = *(const float4*)(in + i * 8);
    float4 b = *(const float4*)(in + i * 8 + 4);
    ushort o[8] = {bf16_rne(a.x), bf16_rne(a.y), bf16_rne(a.z), bf16_rne(a.w),
                   bf16_rne(b.x), bf16_rne(b.y), bf16_rne(b.z), bf16_rne(b.w)};
    *(bf16x8*)(out + i * 8) = *(bf16x8*)o;
}

// ---- transpose+cast W[k][n] f32 -> Wt[n][k] bf16, two weights in one launch ----
__global__ __launch_bounds__(256) void castWt_kernel(const float* __restrict__ W0,
                                                     const float* __restrict__ W1,
                                                     ushort* __restrict__ Wt0,
                                                     ushort* __restrict__ Wt1) {
    const float* W = (blockIdx.x < 256) ? W0 : W1;
    ushort* Wt = (blockIdx.x < 256) ? Wt0 : Wt1;
    int n = blockIdx.x & 255;
    int k = threadIdx.x;
    Wt[n * 256 + k] = bf16_rne(W[k * 256 + n]);
}

// ---------------- GEMM: Cbf[M,256]bf16 = A[M,256]bf16 @ Bt[n][k]bf16 ----------------
// 128x128 tile, BK=64, 256 threads (4 waves 2x2), 16x16x32 MFMA, XOR-swizzled LDS.
// Fused epilogue: el/er = dot(feat_row, al/ar) per head (16-lane shfl reduce).
__global__ __launch_bounds__(256) void gemm_bf16(const ushort* __restrict__ A,
                                                 const ushort* __restrict__ Bt,
                                                 ushort* __restrict__ Cbf,
                                                 const float* __restrict__ al,
                                                 const float* __restrict__ ar,
                                                 float* __restrict__ el,
                                                 float* __restrict__ er, int M) {
    __shared__ __align__(16) ushort As[128 * 64];   // [row][k], 16B blocks XOR-swizzled
    __shared__ __align__(16) ushort Bs[128 * 64];   // [col][k], same
    const int t = threadIdx.x;
    const int l = t & 63;
    const int w = t >> 6;
    const int wm = (w >> 1) * 64, wn = (w & 1) * 64;
    const int m0 = blockIdx.x * 128, n0 = blockIdx.y * 128;
    const int lr = l & 15, lk = l >> 4;

    f32x4 acc[4][4] = {};
    const int sr = t >> 3;            // staging row-in-issue 0..31
    const int sc = t & 7;             // global 16B-block col
    const int scw = sc ^ (sr & 7);    // swizzled LDS block

    for (int k0 = 0; k0 < 256; k0 += 64) {
        #pragma unroll
        for (int q = 0; q < 4; ++q) {
            int row = q * 32 + sr;
            int ga = min(m0 + row, M - 1);
            bf16x8 va = *(const bf16x8*)(A + (size_t)ga * 256 + k0 + sc * 8);
            *(bf16x8*)(&As[row * 64 + scw * 8]) = va;
            bf16x8 vb = *(const bf16x8*)(Bt + (size_t)(n0 + row) * 256 + k0 + sc * 8);
            *(bf16x8*)(&Bs[row * 64 + scw * 8]) = vb;
        }
        __syncthreads();
        #pragma unroll
        for (int kk = 0; kk < 2; ++kk) {
            bf16x8 af[4], bfr[4];
            #pragma unroll
            for (int mi = 0; mi < 4; ++mi) {
                int row = wm + mi * 16 + lr;
                int kb = kk * 4 + lk;
                af[mi] = *(const bf16x8*)(&As[row * 64 + (kb ^ (row & 7)) * 8]);
            }
            #pragma unroll
            for (int ni = 0; ni < 4; ++ni) {
                int col = wn + ni * 16 + lr;
                int kb = kk * 4 + lk;
                bfr[ni] = *(const bf16x8*)(&Bs[col * 64 + (kb ^ (col & 7)) * 8]);
            }
            #pragma unroll
            for (int mi = 0; mi < 4; ++mi)
                #pragma unroll
                for (int ni = 0; ni < 4; ++ni)
                    acc[mi][ni] = __builtin_amdgcn_mfma_f32_16x16x32_bf16(af[mi], bfr[ni], acc[mi][ni], 0, 0, 0);
        }
        __syncthreads();
    }
    // this wave's head and its al/ar slice (d = ni*16 + lr)
    const int h = (n0 + wn) >> 6;
    float alv[4], arv[4];
    #pragma unroll
    for (int ni = 0; ni < 4; ++ni) {
        alv[ni] = al[h * ND + ni * 16 + lr];
        arv[ni] = ar[h * ND + ni * 16 + lr];
    }
    // C/D layout: col = lane&15, row = (lane>>4)*4 + reg  [m89-verified]
    #pragma unroll
    for (int mi = 0; mi < 4; ++mi) {
        #pragma unroll
        for (int j = 0; j < 4; ++j) {
            int row = m0 + wm + mi * 16 + lk * 4 + j;
            float pe = 0.f, pr = 0.f;
            #pragma unroll
            for (int ni = 0; ni < 4; ++ni) {
                float v = acc[mi][ni][j];
                pe += v * alv[ni];
                pr += v * arv[ni];
                if (row < M)
                    Cbf[(size_t)row * 256 + n0 + wn + ni * 16 + lr] = bf16_rne(v);
            }
            #pragma unroll
            for (int m = 1; m <= 8; m <<= 1) {
                pe += __shfl_xor(pe, m, 64);
                pr += __shfl_xor(pr, m, 64);
            }
            if (lr == 0 && row < M) {
                el[row * 4 + h] = pe;
                er[row * 4 + h] = pr;
            }
        }
    }
}

// -------- CSR build --------
__global__ __launch_bounds__(256) void hist_kernel(const int* __restrict__ dst, int* __restrict__ count) {
    int e = blockIdx.x * 256 + threadIdx.x;
    if (e < N_EDGES) atomicAdd(&count[dst[e]], 1);
}

__global__ __launch_bounds__(256) void scan1_kernel(const int* __restrict__ counts,
                                                    int* __restrict__ offs,
                                                    int* __restrict__ bsums) {
    __shared__ int sh[256];
    int tid = threadIdx.x;
    int i = blockIdx.x * 256 + tid;
    int v = (i < N_NODES) ? counts[i] : 0;
    sh[tid] = v;
    __syncthreads();
    #pragma unroll
    for (int ofs = 1; ofs < 256; ofs <<= 1) {
        int t = (tid >= ofs) ? sh[tid - ofs] : 0;
        __syncthreads();
        sh[tid] += t;
        __syncthreads();
    }
    if (i < N_NODES) offs[i] = sh[tid] - v;
    if (tid == 255) bsums[blockIdx.x] = sh[255];
}

__global__ __launch_bounds__(256) void scan2_kernel(const int* __restrict__ bsums,
                                                    int* __restrict__ boffs, int nb) {
    __shared__ int sh[256];
    int tid = threadIdx.x;
    int v = (tid < nb) ? bsums[tid] : 0;
    sh[tid] = v;
    __syncthreads();
    #pragma unroll
    for (int ofs = 1; ofs < 256; ofs <<= 1) {
        int t = (tid >= ofs) ? sh[tid - ofs] : 0;
        __syncthreads();
        sh[tid] += t;
        __syncthreads();
    }
    if (tid < nb) boffs[tid] = sh[tid] - v;
}

// scan3: finalize offs AND init cursor (absolute write positions)
__global__ __launch_bounds__(256) void scan3_kernel(int* __restrict__ offs,
                                                    const int* __restrict__ boffs,
                                                    int* __restrict__ cursor) {
    int i = blockIdx.x * 256 + threadIdx.x;
    if (i < N_NODES) {
        int v = offs[i] + boffs[i >> 8];
        offs[i] = v;
        cursor[i] = v;
    }
    if (i == 0) offs[N_NODES] = N_EDGES;
}

// scatter: store src node id per slot
__global__ __launch_bounds__(256) void scatter_kernel(const int* __restrict__ src,
                                                      const int* __restrict__ dst,
                                                      int* __restrict__ cursor,
                                                      int* __restrict__ csrc) {
    int e = blockIdx.x * 256 + threadIdx.x;
    if (e >= N_EDGES) return;
    int p = atomicAdd(&cursor[dst[e]], 1);
    csrc[p] = src[e];
}

// -------- aggregation: async LDS row staging, weights inline via LDS, NO per-thread arrays --------
// one wave per node. Per 16-edge chunk:
//   all lanes: sidv = csrc[min(i+(lane&15), s1-1)]   (coalesced, no array)
//   lanes 0-15: gather el[sidv], w4 = exp(leaky(el+er_n)) tail-zeroed -> ds_write to myw
//   8x dual-row global_load_lds (row ids via readlane -> SGPR)
//   vmcnt(0) + lgkmcnt(0), then FMA from LDS (feat rows + weights)
#define AGG_STAGE_LOOP()                                                          \
    for (int i = s0; i < s1; i += AGG_CHUNK) {                                    \
        asm volatile("s_waitcnt lgkmcnt(0)" ::: "memory");                        \
        __builtin_amdgcn_sched_barrier(0);                                        \
        int slot = lane & 15;                                                     \
        int idx = min(i + slot, s1 - 1);                                          \
        int sidv = csrc[idx];                                                     \
        if (lane < 16) {                                                          \
            float4 el4 = *(const float4*)(el + sidv * 4);                         \
            float w0 = el4.x + ern.x, w1 = el4.y + ern.y,                         \
                  w2 = el4.z + ern.z, w3 = el4.w + ern.w;                         \
            w0 = w0 > 0.f ? w0 : NEG_SLOPE * w0;                                  \
            w1 = w1 > 0.f ? w1 : NEG_SLOPE * w1;                                  \
            w2 = w2 > 0.f ? w2 : NEG_SLOPE * w2;                                  \
            w3 = w3 > 0.f ? w3 : NEG_SLOPE * w3;                                  \
            bool live = (i + slot) < s1;                                          \
            float4 w4;                                                           \
            w4.x = live ? __expf(w0) : 0.f;                                       \
            w4.y = live ? __expf(w1) : 0.f;                                       \
            w4.z = live ? __expf(w2) : 0.f;                                       \
            w4.w = live ? __expf(w3) : 0.f;                                       \
            *(float4*)(myw + slot * 4) = w4;                                      \
        }                                                                         \
        _Pragma("unroll")                                                         \
        for (int u = 0; u < AGG_CHUNK / 2; ++u) {                                 \
            int sA = __builtin_amdgcn_readlane(sidv, 2 * u);                      \
            int sB = __builtin_amdgcn_readlane(sidv, 2 * u + 1);                  \
            int s2 = rowsel ? sB : sA;                                            \
            row_pair_to_lds(featbf + (size_t)s2 * NF + bsub * 8, myl + u * 1024); \
        }                                                                         \
        asm volatile("s_waitcnt vmcnt(0) lgkmcnt(0)" ::: "memory");               \
        __builtin_amdgcn_sched_barrier(0);                                        \
        _Pragma("unroll")                                                         \
        for (int u = 0; u < AGG_CHUNK; ++u) {                                     \
            ushort4 fr = *(const ushort4*)(myl + u * 512 + lane * 8);             \
            float wu = myw[u * 4 + h];                                            \
            dsum += wu;                                                           \
            acc.x += wu * bf2f(fr.x);                                             \
            acc.y += wu * bf2f(fr.y);                                             \
            acc.z += wu * bf2f(fr.z);                                             \
            acc.w += wu * bf2f(fr.w);                                             \
        }                                                                         \
    }

#define AGG_PREAMBLE()                                                            \
    __shared__ __align__(16) char ldsbuf[4][AGG_CHUNK * 512];                     \
    __shared__ __align__(16) float ldsw[4][AGG_CHUNK * 4];                        \
    int wid = threadIdx.x >> 6;                                                   \
    char* myl = &ldsbuf[wid][0];                                                  \
    float* myw = &ldsw[wid][0];                                                   \
    int n = __builtin_amdgcn_readfirstlane(blockIdx.x * 4 + wid);                 \
    int lane = threadIdx.x & 63;                                                  \
    int h = lane >> 4;                                                            \
    int rowsel = lane >> 5;                                                       \
    int bsub = lane & 31;                                                         \
    int s0 = __builtin_amdgcn_readfirstlane(offs[n]);                             \
    int s1 = __builtin_amdgcn_readfirstlane(offs[n + 1]);                         \
    float4 ern = *(const float4*)(er + n * 4);                                    \
    float4 acc = make_float4(0.f, 0.f, 0.f, 0.f);                                 \
    float dsum = 0.f;

__global__ __launch_bounds__(256) void agg_l0_kernel(const ushort* __restrict__ featbf,
                                                     const int* __restrict__ csrc,
                                                     const int* __restrict__ offs,
                                                     const float* __restrict__ el,
                                                     const float* __restrict__ er,
                                                     ushort* __restrict__ out_bf) {
    AGG_PREAMBLE()
    AGG_STAGE_LOOP()
    float inv = 1.f / fmaxf(dsum, 1e-9f);
    ushort o[4] = {bf16_rne(elu_f(acc.x * inv)), bf16_rne(elu_f(acc.y * inv)),
                   bf16_rne(elu_f(acc.z * inv)), bf16_rne(elu_f(acc.w * inv))};
    *(ushort4*)(out_bf + (size_t)n * NF + lane * 4) = *(ushort4*)o;
}

// -------- final: aggregation + elu + heads write + cluster softmax --------
__global__ __launch_bounds__(256) void agg_final_kernel(const ushort* __restrict__ featbf,
                                                        const int* __restrict__ csrc,
                                                        const int* __restrict__ offs,
                                                        const float* __restrict__ el,
                                                        const float* __restrict__ er,
                                                        const float* __restrict__ Wc,
                                                        const float* __restrict__ bc,
                                                        float* __restrict__ out) {
    AGG_PREAMBLE()
    AGG_STAGE_LOOP()
    int g = lane & 15;
    float inv = 1.f / fmaxf(dsum, 1e-9f);
    float v0 = elu_f(acc.x * inv), v1 = elu_f(acc.y * inv);
    float v2 = elu_f(acc.z * inv), v3 = elu_f(acc.w * inv);
    size_t base = (size_t)h * N_NODES * (ND + NC) + (size_t)n * (ND + NC);
    *(float4*)(out + base + g * 4) = make_float4(v0, v1, v2, v3);
    float logit[NC];
    #pragma unroll
    for (int c = 0; c < NC; ++c) {
        int d0 = g * 4;
        float p = v0 * Wc[(d0 + 0) * NC + c] + v1 * Wc[(d0 + 1) * NC + c] +
                  v2 * Wc[(d0 + 2) * NC + c] + v3 * Wc[(d0 + 3) * NC + c];
        p += __shfl_xor(p, 1, 64);
        p += __shfl_xor(p, 2, 64);
        p += __shfl_xor(p, 4, 64);
        p += __shfl_xor(p, 8, 64);
        logit[c] = p + bc[c];
    }
    float m = logit[0];
    #pragma unroll
    for (int c = 1; c < NC; ++c) m = fmaxf(m, logit[c]);
    float ssum = 0.f;
    #pragma unroll
    for (int c = 0; c < NC; ++c) ssum += __expf(logit[c] - m);
    out[base + ND + g] = __expf(logit[g] - m) / ssum;
}

extern "C" void kernel_launch(void* const* d_in, const int* in_sizes, int n_in,
                              void* d_out, int out_size, void* d_ws, size_t ws_size,
                              hipStream_t stream) {
    const float* x   = (const float*)d_in[0];
    const int* src   = (const int*)d_in[1];
    const int* dst   = (const int*)d_in[2];
    const float* W0  = (const float*)d_in[3];
    const float* al0 = (const float*)d_in[4];
    const float* ar0 = (const float*)d_in[5];
    const float* W1  = (const float*)d_in[6];
    const float* al1 = (const float*)d_in[7];
    const float* ar1 = (const float*)d_in[8];
    const float* Wc  = (const float*)d_in[9];
    const float* bc  = (const float*)d_in[10];
    float* out = (float*)d_out;

    char* ws = (char*)d_ws;
    size_t off = 0;
    auto alloc = [&](size_t bytes) { void* p = ws + off; off = (off + bytes + 255) & ~(size_t)255; return p; };
    ushort* featbf = (ushort*)alloc((size_t)N_NODES * NF * 2);   // 25.6 MB (GEMM out, bf16)
    ushort* xbf    = (ushort*)alloc((size_t)N_NODES * NF * 2);   // 25.6 MB
    ushort* hbuf   = (ushort*)alloc((size_t)N_NODES * NF * 2);   // 25.6 MB (layer0 out, bf16)
    ushort* Wt0    = (ushort*)alloc((size_t)256 * 256 * 2);
    ushort* Wt1    = (ushort*)alloc((size_t)256 * 256 * 2);
    float*  el     = (float*)alloc((size_t)N_NODES * NH * 4);
    float*  er     = (float*)alloc((size_t)N_NODES * NH * 4);
    int* counts    = (int*)alloc((size_t)N_NODES * 4);
    int* offs      = (int*)alloc((size_t)(N_NODES + 1) * 4);
    int* cursor    = (int*)alloc((size_t)N_NODES * 4);
    int* csrc      = (int*)alloc((size_t)N_EDGES * 4);
    int* bsums     = (int*)alloc(256 * 4);
    int* boffs     = (int*)alloc(256 * 4);

    const int EB = (N_EDGES + 255) / 256;          // 3125
    const int NB = (N_NODES + 255) / 256;          // 196
    const int GEMM_MB = (N_NODES + 127) / 128;     // 391
    const int C8 = (N_NODES * NF / 8 + 255) / 256;

    // ---- CSR build (stores src ids per slot) ----
    hipMemsetAsync(counts, 0, (size_t)N_NODES * 4, stream);
    hist_kernel<<<EB, 256, 0, stream>>>(dst, counts);
    scan1_kernel<<<NB, 256, 0, stream>>>(counts, offs, bsums);
    scan2_kernel<<<1, 256, 0, stream>>>(bsums, boffs, NB);
    scan3_kernel<<<NB, 256, 0, stream>>>(offs, boffs, cursor);
    scatter_kernel<<<EB, 256, 0, stream>>>(src, dst, cursor, csrc);

    // ---- weight + input casts ----
    castWt_kernel<<<512, 256, 0, stream>>>(W0, W1, Wt0, Wt1);
    cast_bf16_kernel<<<C8, 256, 0, stream>>>(x, xbf, N_NODES * NF / 8);

    // ---- Layer 0 ----
    gemm_bf16<<<dim3(GEMM_MB, 2), 256, 0, stream>>>(xbf, Wt0, featbf, al0, ar0, el, er, N_NODES);
    agg_l0_kernel<<<N_NODES / 4, 256, 0, stream>>>(featbf, csrc, offs, el, er, hbuf);

    // ---- Layer 1 ----
    gemm_bf16<<<dim3(GEMM_MB, 2), 256, 0, stream>>>(hbuf, Wt1, featbf, al1, ar1, el, er, N_NODES);
    agg_final_kernel<<<N_NODES / 4, 256, 0, stream>>>(featbf, csrc, offs, el, er, Wc, bc, out);
}